// Round 5
// baseline (1219.623 us; speedup 1.0000x reference)
//
#include <hip/hip_runtime.h>

// ---------------------------------------------------------------------------
// SpatiotemporalSlotAttention on MI355X (gfx950). B=16,S=4096,D=1024,K=16,3 it.
// Round 8: dispatch-count reduction (serial-stage latency was ~half the time).
//  - attn_pass1+pass2 fused (p in LDS, PV from L2-resident tok tile).
//  - qdot folded into ln (bq.bk term dropped: softmax-invariant; qd scaled).
//  - MLP-ln folded into gru; gi+gh GEMMs merged (grid.z=2).
//  - normcvt self-clears updates; ln zeroes rowsum; W2-GEMM of last iter
//    writes d_out directly. 13 -> 8 dispatches per iteration.
// ---------------------------------------------------------------------------

typedef unsigned short u16;
typedef unsigned int u32;
typedef float f32x4 __attribute__((ext_vector_type(4)));
typedef unsigned int u32x2 __attribute__((ext_vector_type(2)));
typedef unsigned int u32x4 __attribute__((ext_vector_type(4)));
typedef __bf16 bf16x8 __attribute__((ext_vector_type(8)));

#define B_ 16
#define S_ 4096
#define D_ 1024
#define K_ 16
#define SCALE_ 0.03125f

__device__ __forceinline__ float b2f(u16 u) {
  u32 x = ((u32)u) << 16;
  return __builtin_bit_cast(float, x);
}
__device__ __forceinline__ u16 f2b(float f) {
  u32 u = __builtin_bit_cast(u32, f);
  u32 r = (u + 0x7fffu + ((u >> 16) & 1u)) >> 16;  // RNE
  return (u16)r;
}
__device__ __forceinline__ bf16x8 ld16g(const u16* p) {
  return __builtin_bit_cast(bf16x8, *(const u32x4*)p);
}
__device__ __forceinline__ void gload_lds16(const void* g, void* l) {
  __builtin_amdgcn_global_load_lds(
      (const __attribute__((address_space(1))) void*)g,
      (__attribute__((address_space(3))) void*)l, 16, 0, 0);
}

// fp32 -> bf16, 8 elements/thread (vectorized: 32B in, 16B out)
__global__ void convert8_kernel(const float* __restrict__ src,
                                u16* __restrict__ dst, int n8) {
  const int idx = blockIdx.x * 256 + threadIdx.x;
  if (idx >= n8) return;
  const float* s = src + (size_t)idx * 8;
  const f32x4 lo = *(const f32x4*)s;
  const f32x4 hi = *(const f32x4*)(s + 4);
  union { u16 h[8]; u32x4 q; } u;
#pragma unroll
  for (int j = 0; j < 4; ++j) { u.h[j] = f2b(lo[j]); u.h[4 + j] = f2b(hi[j]); }
  *(u32x4*)(dst + (size_t)idx * 8) = u.q;
}

// fp32 [R x C] -> bf16 transposed [C x R]. 64x64 tiles, coalesced reads.
__global__ __launch_bounds__(256) void transcvt_kernel(
    const float* __restrict__ src, u16* __restrict__ dst, int R, int C) {
  const int r0 = blockIdx.x * 64;
  const int c0 = blockIdx.y * 64;
  const int cl = threadIdx.x & 63;
  const int rq = threadIdx.x >> 6;  // 0..3
#pragma unroll
  for (int h = 0; h < 2; ++h) {
    const int rbase = (rq + h * 4) * 8;
    union { u16 u[8]; u32x4 q; } w;
#pragma unroll
    for (int j = 0; j < 8; ++j)
      w.u[j] = f2b(src[(size_t)(r0 + rbase + j) * C + c0 + cl]);
    *(u32x4*)&dst[(size_t)(c0 + cl) * R + r0 + rbase] = w.q;
  }
}

// out[c] += sum_{r in block-chunk} W[r*C+c] * x[r]
// split-R: grid (C/256, R/64); out must be zeroed before launch.
__global__ void colvec_kernel(const float* __restrict__ W,
                              const float* __restrict__ x,
                              float* __restrict__ out, int R, int C) {
  const int c = blockIdx.x * 256 + threadIdx.x;
  const int r0 = blockIdx.y * 64;
  if (c >= C) return;
  float acc = 0.f;
#pragma unroll 8
  for (int r = 0; r < 64; ++r)
    acc = fmaf(W[(size_t)(r0 + r) * C + c], x[r0 + r], acc);
  atomicAdd(&out[c], acc);
}

// out[r] = add[r] + sum_c W[r*C+c] * x[c]   (one wave per row; prologue only)
__global__ __launch_bounds__(256) void rowvec_kernel(
    const float* __restrict__ W, const float* __restrict__ x,
    const float* __restrict__ add, float* __restrict__ out, int R, int C) {
  const int wave = threadIdx.x >> 6, lane = threadIdx.x & 63;
  const int r = blockIdx.x * 4 + wave;
  if (r >= R) return;
  float acc = 0.f;
  for (int c = lane; c < C; c += 64) acc = fmaf(W[(size_t)r * C + c], x[c], acc);
#pragma unroll
  for (int off = 1; off < 64; off <<= 1) acc += __shfl_xor(acc, off);
  if (lane == 0) out[r] = add[r] + acc;
}

// ---------------------------------------------------------------------------
// Big bt-GEMM: C(bf16, MxN) = A(bf16 MxKd) @ Bw(bf16 NxKd)^T [+ bias].
// 128x128 tile, 4 waves, global_load_lds staging, both-sides XOR swizzle,
// XCD-chunked 1D grid (nwg % 8 == 0). Prologue-only (P^T, Wihv).
// ---------------------------------------------------------------------------
__global__ __launch_bounds__(256) void gemm128_bb(
    const u16* __restrict__ A, const u16* __restrict__ Bw,
    const float* __restrict__ bias, u16* __restrict__ C, int N, int Kd,
    int mtiles) {
  __shared__ __align__(16) u16 At[128 * 64];
  __shared__ __align__(16) u16 Bt[128 * 64];
  const int tid = threadIdx.x;
  const int ntiles = N >> 7;
  const int nwg = mtiles * ntiles;
  const int cpx = nwg >> 3;  // blocks per XCD (nwg % 8 == 0)
  const int lin = blockIdx.x;
  const int wg = (lin & 7) * cpx + (lin >> 3);
  const int m0 = (wg / ntiles) * 128;
  const int n0 = (wg % ntiles) * 128;
  const int wave = tid >> 6, lane = tid & 63;
  const int q4 = lane >> 4, l16 = lane & 15;
  const int wm = (wave & 1) * 64, wn = (wave >> 1) * 64;

  f32x4 acc[4][4];
#pragma unroll
  for (int i = 0; i < 4; ++i)
#pragma unroll
    for (int j = 0; j < 4; ++j) acc[i][j] = 0.f;

  const int trow = tid >> 3;                             // 0..31
  const int tcol = ((tid & 7) * 8) ^ ((trow & 7) << 3);  // pre-swizzled col
  const u16* ga = A + (size_t)(m0 + trow) * Kd + tcol;
  const u16* gb = Bw + (size_t)(n0 + trow) * Kd + tcol;
  u16* la = At + tid * 8;
  u16* lb = Bt + tid * 8;

  for (int k0 = 0; k0 < Kd; k0 += 64) {
    __syncthreads();
#pragma unroll
    for (int c = 0; c < 4; ++c)
      gload_lds16(ga + (size_t)c * 32 * Kd + k0, la + c * 2048);
#pragma unroll
    for (int c = 0; c < 4; ++c)
      gload_lds16(gb + (size_t)c * 32 * Kd + k0, lb + c * 2048);
    __syncthreads();
#pragma unroll
    for (int kk = 0; kk < 64; kk += 32) {
      bf16x8 af[4], bfr[4];
#pragma unroll
      for (int i = 0; i < 4; ++i) {
        const int row = wm + i * 16 + l16;
        const int byo = row * 128 + ((kk * 2 + q4 * 16) ^ ((row & 7) << 4));
        af[i] = *(const bf16x8*)((const char*)At + byo);
      }
#pragma unroll
      for (int j = 0; j < 4; ++j) {
        const int row = wn + j * 16 + l16;
        const int byo = row * 128 + ((kk * 2 + q4 * 16) ^ ((row & 7) << 4));
        bfr[j] = *(const bf16x8*)((const char*)Bt + byo);
      }
#pragma unroll
      for (int i = 0; i < 4; ++i)
#pragma unroll
        for (int j = 0; j < 4; ++j)
          acc[i][j] = __builtin_amdgcn_mfma_f32_16x16x32_bf16(af[i], bfr[j],
                                                              acc[i][j], 0, 0, 0);
    }
  }
#pragma unroll
  for (int j = 0; j < 4; ++j) {
    const int col = n0 + wn + j * 16 + l16;
    const float bv = bias ? bias[col] : 0.f;
#pragma unroll
    for (int i = 0; i < 4; ++i) {
      const int rowb = m0 + wm + i * 16 + q4 * 4;
#pragma unroll
      for (int r = 0; r < 4; ++r)
        C[(size_t)(rowb + r) * N + col] = f2b(acc[i][j][r] + bv);
    }
  }
}

// ---------------------------------------------------------------------------
// Small bt-GEMM (M=256): 64x64 tile, 4 waves of 32x32. A,Bw bf16, bias fp32.
// Both-sides XOR swizzle. MODE 0: bf16 out | 2: gelu->bf16 | 3: +resid->f32
// ---------------------------------------------------------------------------
template <int MODE>
__global__ __launch_bounds__(256) void gemm64_bt(
    const u16* __restrict__ A, const u16* __restrict__ Bw,
    const float* __restrict__ bias, float* Cf, u16* Cb, const float* resid,
    int N, int Kd) {
  __shared__ __align__(16) u16 At[64 * 64];
  __shared__ __align__(16) u16 Bt[64 * 64];
  const int tid = threadIdx.x;
  const int m0 = blockIdx.x * 64;
  const int n0 = blockIdx.y * 64;
  const int wave = tid >> 6, lane = tid & 63;
  const int q4 = lane >> 4, l16 = lane & 15;
  const int wm = (wave & 1) * 32, wn = (wave >> 1) * 32;

  f32x4 acc[2][2];
#pragma unroll
  for (int i = 0; i < 2; ++i)
#pragma unroll
    for (int j = 0; j < 2; ++j) acc[i][j] = 0.f;

  const int r_ = tid >> 3;
  const int c8 = (tid & 7) * 8;
  const int c8s = c8 ^ ((r_ & 7) << 3);  // swizzled store col

  for (int k0 = 0; k0 < Kd; k0 += 64) {
    u32x4 ta[2], tb[2];
#pragma unroll
    for (int i = 0; i < 2; ++i) {
      ta[i] = *(const u32x4*)(A + (size_t)(m0 + r_ + i * 32) * Kd + k0 + c8);
      tb[i] = *(const u32x4*)(Bw + (size_t)(n0 + r_ + i * 32) * Kd + k0 + c8);
    }
    __syncthreads();
#pragma unroll
    for (int i = 0; i < 2; ++i) {
      *(u32x4*)&At[(r_ + i * 32) * 64 + c8s] = ta[i];
      *(u32x4*)&Bt[(r_ + i * 32) * 64 + c8s] = tb[i];
    }
    __syncthreads();
#pragma unroll
    for (int kk = 0; kk < 64; kk += 32) {
      bf16x8 af[2], bfr[2];
#pragma unroll
      for (int i = 0; i < 2; ++i) {
        const int row = wm + i * 16 + l16;
        const int byo = row * 128 + ((kk * 2 + q4 * 16) ^ ((row & 7) << 4));
        af[i] = *(const bf16x8*)((const char*)At + byo);
      }
#pragma unroll
      for (int j = 0; j < 2; ++j) {
        const int row = wn + j * 16 + l16;
        const int byo = row * 128 + ((kk * 2 + q4 * 16) ^ ((row & 7) << 4));
        bfr[j] = *(const bf16x8*)((const char*)Bt + byo);
      }
#pragma unroll
      for (int i = 0; i < 2; ++i)
#pragma unroll
        for (int j = 0; j < 2; ++j)
          acc[i][j] = __builtin_amdgcn_mfma_f32_16x16x32_bf16(af[i], bfr[j],
                                                              acc[i][j], 0, 0, 0);
    }
  }
#pragma unroll
  for (int j = 0; j < 2; ++j) {
    const int col = n0 + wn + j * 16 + l16;
    const float bv = bias[col];
#pragma unroll
    for (int i = 0; i < 2; ++i) {
      const int rowb = m0 + wm + i * 16 + q4 * 4;
#pragma unroll
      for (int r = 0; r < 4; ++r) {
        const int row = rowb + r;
        float val = acc[i][j][r] + bv;
        if constexpr (MODE == 0) {
          Cb[(size_t)row * N + col] = f2b(val);
        } else if constexpr (MODE == 2) {
          val = 0.5f * val * (1.f + erff(val * 0.70710678118654752f));
          Cb[(size_t)row * N + col] = f2b(val);
        } else {
          const float rv = resid[(size_t)row * N + col];
          Cf[(size_t)row * N + col] = val + rv;
        }
      }
    }
  }
}

// Dual small GEMM (gi and gh in one dispatch; blockIdx.z selects). f32 out.
__global__ __launch_bounds__(256) void gemm64_dual(
    const u16* __restrict__ A0, const u16* __restrict__ A1,
    const u16* __restrict__ B0, const u16* __restrict__ B1,
    const float* __restrict__ bias0, const float* __restrict__ bias1,
    float* C0, float* C1, int N, int Kd) {
  const u16* A = blockIdx.z ? A1 : A0;
  const u16* Bw = blockIdx.z ? B1 : B0;
  const float* bias = blockIdx.z ? bias1 : bias0;
  float* Cf = blockIdx.z ? C1 : C0;
  __shared__ __align__(16) u16 At[64 * 64];
  __shared__ __align__(16) u16 Bt[64 * 64];
  const int tid = threadIdx.x;
  const int m0 = blockIdx.x * 64;
  const int n0 = blockIdx.y * 64;
  const int wave = tid >> 6, lane = tid & 63;
  const int q4 = lane >> 4, l16 = lane & 15;
  const int wm = (wave & 1) * 32, wn = (wave >> 1) * 32;

  f32x4 acc[2][2];
#pragma unroll
  for (int i = 0; i < 2; ++i)
#pragma unroll
    for (int j = 0; j < 2; ++j) acc[i][j] = 0.f;

  const int r_ = tid >> 3;
  const int c8 = (tid & 7) * 8;
  const int c8s = c8 ^ ((r_ & 7) << 3);

  for (int k0 = 0; k0 < Kd; k0 += 64) {
    u32x4 ta[2], tb[2];
#pragma unroll
    for (int i = 0; i < 2; ++i) {
      ta[i] = *(const u32x4*)(A + (size_t)(m0 + r_ + i * 32) * Kd + k0 + c8);
      tb[i] = *(const u32x4*)(Bw + (size_t)(n0 + r_ + i * 32) * Kd + k0 + c8);
    }
    __syncthreads();
#pragma unroll
    for (int i = 0; i < 2; ++i) {
      *(u32x4*)&At[(r_ + i * 32) * 64 + c8s] = ta[i];
      *(u32x4*)&Bt[(r_ + i * 32) * 64 + c8s] = tb[i];
    }
    __syncthreads();
#pragma unroll
    for (int kk = 0; kk < 64; kk += 32) {
      bf16x8 af[2], bfr[2];
#pragma unroll
      for (int i = 0; i < 2; ++i) {
        const int row = wm + i * 16 + l16;
        const int byo = row * 128 + ((kk * 2 + q4 * 16) ^ ((row & 7) << 4));
        af[i] = *(const bf16x8*)((const char*)At + byo);
      }
#pragma unroll
      for (int j = 0; j < 2; ++j) {
        const int row = wn + j * 16 + l16;
        const int byo = row * 128 + ((kk * 2 + q4 * 16) ^ ((row & 7) << 4));
        bfr[j] = *(const bf16x8*)((const char*)Bt + byo);
      }
#pragma unroll
      for (int i = 0; i < 2; ++i)
#pragma unroll
        for (int j = 0; j < 2; ++j)
          acc[i][j] = __builtin_amdgcn_mfma_f32_16x16x32_bf16(af[i], bfr[j],
                                                              acc[i][j], 0, 0, 0);
    }
  }
#pragma unroll
  for (int j = 0; j < 2; ++j) {
    const int col = n0 + wn + j * 16 + l16;
    const float bv = bias[col];
#pragma unroll
    for (int i = 0; i < 2; ++i) {
      const int rowb = m0 + wm + i * 16 + q4 * 4;
#pragma unroll
      for (int r = 0; r < 4; ++r)
        Cf[(size_t)(rowb + r) * N + col] = acc[i][j][r] + bv;
    }
  }
}

// ---------------------------------------------------------------------------
// Fused attention: phase 1 = logits -> softmax over slots -> p (LDS) +
// rowsum atomics (+ optional attn out). phase 2 = updates += p^T @ tok.
// One block = (batch b, 256-token chunk).
// ---------------------------------------------------------------------------
__global__ __launch_bounds__(256) void attn_fused(
    const u16* __restrict__ qb, const u16* __restrict__ tok,
    const float* __restrict__ qdot, float* __restrict__ rowsum,
    float* __restrict__ updates, float* __restrict__ attn_out) {
  __shared__ float p_lds[256][20];  // pad 20 -> aligned f32x4, spread banks
  const int b = blockIdx.y;
  const int wave = threadIdx.x >> 6, lane = threadIdx.x & 63;
  const int q4 = lane >> 4, l16 = lane & 15;
  const int tokbase = blockIdx.x * 256;
  const int tok0 = tokbase + wave * 64;
  const u16* ap = qb + (size_t)(b * 16 + l16) * D_ + q4 * 8;
  const u16* bp = tok + ((size_t)b * S_ + tok0 + l16) * D_ + q4 * 8;
  const f32x4 qd = *(const f32x4*)&qdot[b * 16 + q4 * 4];
  f32x4 acc[4];
#pragma unroll
  for (int j = 0; j < 4; ++j) acc[j] = 0.f;
  for (int k0 = 0; k0 < D_; k0 += 32) {
    bf16x8 a = ld16g(ap + k0);
#pragma unroll
    for (int j = 0; j < 4; ++j) {
      bf16x8 bb = ld16g(bp + (size_t)j * 16 * D_ + k0);
      acc[j] = __builtin_amdgcn_mfma_f32_16x16x32_bf16(a, bb, acc[j], 0, 0, 0);
    }
  }
  float rs[4] = {0.f, 0.f, 0.f, 0.f};
#pragma unroll
  for (int j = 0; j < 4; ++j) {
    const int tl = wave * 64 + j * 16 + l16;  // local token
    float l[4];
#pragma unroll
    for (int r = 0; r < 4; ++r) l[r] = (acc[j][r] + qd[r]) * SCALE_;
    float mx = fmaxf(fmaxf(l[0], l[1]), fmaxf(l[2], l[3]));
    mx = fmaxf(mx, __shfl_xor(mx, 16));
    mx = fmaxf(mx, __shfl_xor(mx, 32));
    float e[4], ssum = 0.f;
#pragma unroll
    for (int r = 0; r < 4; ++r) { e[r] = __expf(l[r] - mx); ssum += e[r]; }
    ssum += __shfl_xor(ssum, 16);
    ssum += __shfl_xor(ssum, 32);
    const float inv = 1.f / ssum;
    f32x4 p;
#pragma unroll
    for (int r = 0; r < 4; ++r) { p[r] = e[r] * inv; rs[r] += p[r]; }
    *(f32x4*)&p_lds[tl][q4 * 4] = p;
    if (attn_out) {
#pragma unroll
      for (int r = 0; r < 4; ++r)
        attn_out[(size_t)(b * 16 + q4 * 4 + r) * S_ + tokbase + tl] = p[r];
    }
  }
#pragma unroll
  for (int r = 0; r < 4; ++r) {
    float v = rs[r];
    v += __shfl_xor(v, 1);
    v += __shfl_xor(v, 2);
    v += __shfl_xor(v, 4);
    v += __shfl_xor(v, 8);
    if (l16 == 0) atomicAdd(&rowsum[b * 16 + q4 * 4 + r], v);
  }
  __syncthreads();
  // phase 2: each thread owns 4 d-columns; tok tile re-read (L2/L3-hot).
  const int d = threadIdx.x * 4;
  const u16* tp = tok + ((size_t)b * S_ + tokbase) * D_ + d;
  f32x4 acc2[16];
#pragma unroll
  for (int k = 0; k < 16; ++k) acc2[k] = 0.f;
#pragma unroll 2
  for (int s = 0; s < 256; ++s) {
    const u32x2 w = *(const u32x2*)(tp + (size_t)s * D_);
    const float v0 = b2f((u16)(w[0] & 0xffffu));
    const float v1 = b2f((u16)(w[0] >> 16));
    const float v2 = b2f((u16)(w[1] & 0xffffu));
    const float v3 = b2f((u16)(w[1] >> 16));
#pragma unroll
    for (int k4 = 0; k4 < 4; ++k4) {
      const f32x4 pv = *(const f32x4*)&p_lds[s][k4 * 4];
#pragma unroll
      for (int r = 0; r < 4; ++r) {
        const int k = k4 * 4 + r;
        acc2[k][0] = fmaf(pv[r], v0, acc2[k][0]);
        acc2[k][1] = fmaf(pv[r], v1, acc2[k][1]);
        acc2[k][2] = fmaf(pv[r], v2, acc2[k][2]);
        acc2[k][3] = fmaf(pv[r], v3, acc2[k][3]);
      }
    }
  }
  float* up = updates + (size_t)(b * 16) * D_ + d;
#pragma unroll
  for (int k = 0; k < 16; ++k) {
#pragma unroll
    for (int c = 0; c < 4; ++c)
      atomicAdd(&up[(size_t)k * D_ + c], acc2[k][c]);
  }
}

// normcvt: out = bf16(updates / rowsum); self-clears updates for next iter.
__global__ void normcvt_kernel(float* __restrict__ updates,
                               const float* __restrict__ rowsum,
                               u16* __restrict__ out) {
  const int idx = blockIdx.x * 256 + threadIdx.x;
  const int m = idx >> 10;
  const float inv = 1.f / (rowsum[m] + 1e-8f);
  out[idx] = f2b(updates[idx] * inv);
  updates[idx] = 0.f;
}

// LayerNorm (256,1024) f32 -> bf16 (+ raw bf16 copy) + fused qdot
// (qdot[m] = sum_a ln[m,a]*qd_w[a], unscaled) + rowsum zeroing.
__global__ __launch_bounds__(256) void ln_kernel(
    const float* __restrict__ x, const float* __restrict__ g,
    const float* __restrict__ bb, u16* __restrict__ out_ln,
    u16* __restrict__ out_raw, const float* __restrict__ qd_w,
    float* __restrict__ qdot_out, float* __restrict__ rowsum_zero) {
  const int row = blockIdx.x, tid = threadIdx.x;
  const float* xr = x + (size_t)row * D_;
  float v[4], s = 0.f, ss = 0.f;
#pragma unroll
  for (int i = 0; i < 4; ++i) {
    v[i] = xr[tid + i * 256];
    s += v[i];
    ss += v[i] * v[i];
  }
#pragma unroll
  for (int off = 1; off < 64; off <<= 1) {
    s += __shfl_xor(s, off);
    ss += __shfl_xor(ss, off);
  }
  __shared__ float sh[8];
  __shared__ float shq[4];
  if ((tid & 63) == 0) { sh[tid >> 6] = s; sh[4 + (tid >> 6)] = ss; }
  __syncthreads();
  s = sh[0] + sh[1] + sh[2] + sh[3];
  ss = sh[4] + sh[5] + sh[6] + sh[7];
  const float mu = s * (1.f / 1024.f);
  float var = ss * (1.f / 1024.f) - mu * mu;
  var = fmaxf(var, 0.f);
  const float rstd = rsqrtf(var + 1e-5f);
  float qa = 0.f;
#pragma unroll
  for (int i = 0; i < 4; ++i) {
    const int dd = tid + i * 256;
    const float lv = (v[i] - mu) * rstd * g[dd] + bb[dd];
    out_ln[(size_t)row * D_ + dd] = f2b(lv);
    if (out_raw) out_raw[(size_t)row * D_ + dd] = f2b(v[i]);
    if (qd_w) qa = fmaf(lv, qd_w[dd], qa);
  }
  if (qd_w) {
#pragma unroll
    for (int off = 1; off < 64; off <<= 1) qa += __shfl_xor(qa, off);
    if ((tid & 63) == 0) shq[tid >> 6] = qa;
    __syncthreads();
    if (tid == 0) qdot_out[row] = shq[0] + shq[1] + shq[2] + shq[3];
  }
  if (rowsum_zero && tid == 0) rowsum_zero[row] = 0.f;
}

// GRU cell + fused MLP-LayerNorm. One block per row (m = b*K + k).
__global__ __launch_bounds__(256) void gru_ln_kernel(
    const float* __restrict__ gi, const float* __restrict__ gh,
    float* __restrict__ slots, const float* __restrict__ g,
    const float* __restrict__ bb, u16* __restrict__ out_ln) {
  const int row = blockIdx.x, tid = threadIdx.x;
  const size_t gbase = (size_t)row * 3072;
  const size_t sbase = (size_t)row * 1024;
  float v[4], s = 0.f, ss = 0.f;
#pragma unroll
  for (int i = 0; i < 4; ++i) {
    const int dd = tid + i * 256;
    const float ir = gi[gbase + dd], iz = gi[gbase + dd + 1024],
                in_ = gi[gbase + dd + 2048];
    const float hr = gh[gbase + dd], hz = gh[gbase + dd + 1024],
                hn = gh[gbase + dd + 2048];
    const float r = 1.f / (1.f + __expf(-(ir + hr)));
    const float z = 1.f / (1.f + __expf(-(iz + hz)));
    const float n = tanhf(in_ + r * hn);
    const float sv = (1.f - z) * n + z * slots[sbase + dd];
    slots[sbase + dd] = sv;
    v[i] = sv;
    s += sv;
    ss += sv * sv;
  }
#pragma unroll
  for (int off = 1; off < 64; off <<= 1) {
    s += __shfl_xor(s, off);
    ss += __shfl_xor(ss, off);
  }
  __shared__ float sh[8];
  if ((tid & 63) == 0) { sh[tid >> 6] = s; sh[4 + (tid >> 6)] = ss; }
  __syncthreads();
  s = sh[0] + sh[1] + sh[2] + sh[3];
  ss = sh[4] + sh[5] + sh[6] + sh[7];
  const float mu = s * (1.f / 1024.f);
  float var = ss * (1.f / 1024.f) - mu * mu;
  var = fmaxf(var, 0.f);
  const float rstd = rsqrtf(var + 1e-5f);
#pragma unroll
  for (int i = 0; i < 4; ++i) {
    const int dd = tid + i * 256;
    out_ln[sbase + dd] = f2b((v[i] - mu) * rstd * g[dd] + bb[dd]);
  }
}

__global__ void init_slots_kernel(const float* __restrict__ mu,
                                  float* __restrict__ slots) {
  const int idx = blockIdx.x * 256 + threadIdx.x;
  slots[idx] = mu[idx & (K_ * D_ - 1)];
}

// ---------------------------------------------------------------------------
extern "C" void kernel_launch(void* const* d_in, const int* in_sizes, int n_in,
                              void* d_out, int out_size, void* d_ws,
                              size_t ws_size, hipStream_t stream) {
  const float* tokens = (const float*)d_in[0];
  const float* slot_mu = (const float*)d_in[1];
  const float* Wq = (const float*)d_in[2];
  const float* bq = (const float*)d_in[3];
  const float* Wk = (const float*)d_in[4];
  const float* bk = (const float*)d_in[5];
  const float* Wv = (const float*)d_in[6];
  const float* bv = (const float*)d_in[7];
  const float* W_ih = (const float*)d_in[8];
  const float* b_ih = (const float*)d_in[9];
  const float* W_hh = (const float*)d_in[10];
  const float* b_hh = (const float*)d_in[11];
  const float* W1 = (const float*)d_in[12];
  const float* b1 = (const float*)d_in[13];
  const float* W2 = (const float*)d_in[14];
  const float* b2 = (const float*)d_in[15];
  const float* g_slots = (const float*)d_in[16];
  const float* b_slots = (const float*)d_in[17];
  const float* g_mlp = (const float*)d_in[18];
  const float* b_mlp = (const float*)d_in[19];

  char* p = (char*)d_ws;
  auto alloc = [&](size_t bytes) {
    char* r = p;
    p += (bytes + 255) & ~(size_t)255;
    return r;
  };
  u16* tokb = (u16*)alloc((size_t)B_ * S_ * D_ * 2);          // 134 MB bf16 tokens
  float* slots = (float*)alloc((size_t)B_ * K_ * D_ * 4);     // 1 MB
  float* updates = (float*)alloc((size_t)B_ * K_ * D_ * 4);   // 1 MB
  float* rowsum = (float*)alloc(1024);                        // adjacent
  float* gi = (float*)alloc((size_t)B_ * K_ * 3 * D_ * 4);    // 3 MB
  float* gh = (float*)alloc((size_t)B_ * K_ * 3 * D_ * 4);    // 3 MB
  u16* slots_bf16 = (u16*)alloc((size_t)B_ * K_ * D_ * 2);
  u16* slots_ln_bf16 = (u16*)alloc((size_t)B_ * K_ * D_ * 2);
  u16* qkbuf = (u16*)alloc((size_t)B_ * K_ * D_ * 2);
  u16* updates_bf16 = (u16*)alloc((size_t)B_ * K_ * D_ * 2);
  u16* h_bf16 = (u16*)alloc((size_t)B_ * K_ * D_ * 2);
  u16* act_bf16 = (u16*)alloc((size_t)B_ * K_ * 4 * D_ * 2);  // 2 MB
  float* qdotbuf = (float*)alloc(256 * 4);
  float* qd_w = (float*)alloc(D_ * 4);
  float* qkbias = (float*)alloc(D_ * 4);
  float* bihv = (float*)alloc(3 * D_ * 4);
  // bf16 weight copies / fused products
  u16* cWih = (u16*)alloc((size_t)3 * D_ * D_ * 2);
  u16* cWhh = (u16*)alloc((size_t)3 * D_ * D_ * 2);
  u16* cW1 = (u16*)alloc((size_t)4 * D_ * D_ * 2);
  u16* cW2 = (u16*)alloc((size_t)4 * D_ * D_ * 2);
  u16* cWqT = (u16*)alloc((size_t)D_ * D_ * 2);
  u16* cWkT = (u16*)alloc((size_t)D_ * D_ * 2);
  u16* cWvT = (u16*)alloc((size_t)D_ * D_ * 2);
  u16* cPT = (u16*)alloc((size_t)D_ * D_ * 2);        // Wk^T Wq layout
  u16* cWihv = (u16*)alloc((size_t)3 * D_ * D_ * 2);  // W_ih @ Wv
  if ((size_t)(p - (char*)d_ws) > ws_size) return;  // ws too small: bail

  float* out_slots = (float*)d_out;                        // (B,K,D) f32
  float* out_attn = (float*)d_out + (size_t)B_ * K_ * D_;  // (B,K,S) f32

  // ---- prologue ----------------------------------------------------------
  convert8_kernel<<<(3 * D_ * D_ / 8 + 255) / 256, 256, 0, stream>>>(W_ih, cWih, 3 * D_ * D_ / 8);
  convert8_kernel<<<(3 * D_ * D_ / 8 + 255) / 256, 256, 0, stream>>>(W_hh, cWhh, 3 * D_ * D_ / 8);
  convert8_kernel<<<(4 * D_ * D_ / 8 + 255) / 256, 256, 0, stream>>>(W1, cW1, 4 * D_ * D_ / 8);
  convert8_kernel<<<(4 * D_ * D_ / 8 + 255) / 256, 256, 0, stream>>>(W2, cW2, 4 * D_ * D_ / 8);
  convert8_kernel<<<(B_ * S_ * D_ / 8 + 255) / 256, 256, 0, stream>>>(
      tokens, tokb, B_ * S_ * D_ / 8);
  transcvt_kernel<<<dim3(16, 16), 256, 0, stream>>>(Wq, cWqT, D_, D_);
  transcvt_kernel<<<dim3(16, 16), 256, 0, stream>>>(Wk, cWkT, D_, D_);
  transcvt_kernel<<<dim3(16, 16), 256, 0, stream>>>(Wv, cWvT, D_, D_);

  // fused weight products
  gemm128_bb<<<64, 256, 0, stream>>>(cWkT, cWqT, nullptr, cPT, D_, D_, 8);
  gemm128_bb<<<192, 256, 0, stream>>>(cWih, cWvT, nullptr, cWihv, D_, D_, 24);

  // bias folds: qkbias[e]=bq.Wk[:,e]; qd_w[a]=Wq[:,a].bk; bihv=b_ih+W_ih.bv
  // (bq.bk term dropped: constant across slots -> softmax-invariant)
  hipMemsetAsync(qkbias, 0, D_ * 4, stream);
  hipMemsetAsync(qd_w, 0, D_ * 4, stream);
  colvec_kernel<<<dim3(4, 16), 256, 0, stream>>>(Wk, bq, qkbias, D_, D_);
  colvec_kernel<<<dim3(4, 16), 256, 0, stream>>>(Wq, bk, qd_w, D_, D_);
  rowvec_kernel<<<768, 256, 0, stream>>>(W_ih, bv, b_ih, bihv, 3 * D_, D_);

  hipMemsetAsync(updates, 0, (size_t)B_ * K_ * D_ * 4 + 1024, stream);
  init_slots_kernel<<<1024, 256, 0, stream>>>(slot_mu, slots);

  for (int it = 0; it < 3; ++it) {
    // LN + raw copy + qdot + rowsum zero (one dispatch)
    ln_kernel<<<256, 256, 0, stream>>>(slots, g_slots, b_slots, slots_ln_bf16,
                                       slots_bf16, qd_w, qdotbuf, rowsum);
    // qk = lnS @ P + qkbias
    gemm64_bt<0><<<dim3(4, 16), 256, 0, stream>>>(slots_ln_bf16, cPT, qkbias,
                                                  nullptr, qkbuf, nullptr, D_, D_);
    // fused attention (softmax + PV); updates was zeroed by normcvt/memset
    attn_fused<<<dim3(16, 16), 256, 0, stream>>>(
        qkbuf, tokb, qdotbuf, rowsum, updates, (it == 2) ? out_attn : nullptr);
    normcvt_kernel<<<1024, 256, 0, stream>>>(updates, rowsum, updates_bf16);
    // gi = u'n @ Wihv^T + bihv ; gh = slots @ Whh^T + b_hh  (one dispatch)
    gemm64_dual<<<dim3(4, 48, 2), 256, 0, stream>>>(
        updates_bf16, slots_bf16, cWihv, cWhh, bihv, b_hh, gi, gh, 3 * D_, D_);
    // GRU + MLP-LN (one dispatch)
    gru_ln_kernel<<<256, 256, 0, stream>>>(gi, gh, slots, g_mlp, b_mlp, h_bf16);
    gemm64_bt<2><<<dim3(4, 64), 256, 0, stream>>>(h_bf16, cW1, b1, nullptr,
                                                  act_bf16, nullptr, 4 * D_, D_);
    // last iter writes slots directly into d_out
    gemm64_bt<3><<<dim3(4, 16), 256, 0, stream>>>(
        act_bf16, cW2, b2, (it == 2) ? out_slots : slots, nullptr, slots, D_,
        4 * D_);
  }
}